// Round 1
// baseline (965.104 us; speedup 1.0000x reference)
//
#include <hip/hip_runtime.h>

#define N_NODES 100000
#define N_EDGES 1600000
#define CH      128
#define OUT_CH  64
#define NUM_G   64

// ---------------- degree count ----------------
__global__ __launch_bounds__(256) void count_deg(const int* __restrict__ dst,
                                                 int* __restrict__ cnt) {
    int e = blockIdx.x * 256 + threadIdx.x;
    if (e < N_EDGES) atomicAdd(&cnt[dst[e]], 1);
}

__global__ __launch_bounds__(256) void compute_dinv(const int* __restrict__ cnt,
                                                    float* __restrict__ dinv) {
    int n = blockIdx.x * 256 + threadIdx.x;
    if (n < N_NODES) dinv[n] = rsqrtf((float)cnt[n] + 1.0f);
}

// ---------------- single-block exclusive scan (CSR row ptr) ----------------
__global__ __launch_bounds__(1024) void scan_kernel(const int* __restrict__ cnt,
                                                    int* __restrict__ ptr) {
    __shared__ int s_w[16];
    int tid = threadIdx.x, lane = tid & 63, wid = tid >> 6;
    int run = 0;
    for (int base = 0; base < N_NODES; base += 1024) {
        int i = base + tid;
        int v = (i < N_NODES) ? cnt[i] : 0;
        int incl = v;
#pragma unroll
        for (int off = 1; off < 64; off <<= 1) {
            int t = __shfl_up(incl, off);
            if (lane >= off) incl += t;
        }
        if (lane == 63) s_w[wid] = incl;
        __syncthreads();
        if (tid < 16) {
            int w = s_w[tid];
#pragma unroll
            for (int off = 1; off < 16; off <<= 1) {
                int t = __shfl_up(w, off);
                if (tid >= off) w += t;
            }
            s_w[tid] = w;
        }
        __syncthreads();
        int woff = (wid > 0) ? s_w[wid - 1] : 0;
        if (i < N_NODES) ptr[i] = run + woff + incl - v;
        run += s_w[15];
        __syncthreads();
    }
    if (tid == 0) ptr[N_NODES] = run;
}

// ---------------- CSR fill (bucket by dst) ----------------
__global__ __launch_bounds__(256) void fill_csr(const int* __restrict__ src,
                                                const int* __restrict__ dst,
                                                const int* __restrict__ ptr,
                                                int* __restrict__ cursor,
                                                const float* __restrict__ dinv,
                                                int* __restrict__ csr_src,
                                                float* __restrict__ csr_norm) {
    int e = blockIdx.x * 256 + threadIdx.x;
    if (e >= N_EDGES) return;
    int s = src[e], d = dst[e];
    int pos = atomicAdd(&cursor[d], 1);
    int i = ptr[d] + pos;
    csr_src[i]  = s;
    csr_norm[i] = dinv[s] * dinv[d];
}

// ---------------- fp32 GEMM: H[n,128] = A[n,128] @ W[128,128] + b ----------------
// 128x128 output tile per block, BK=16, 256 threads, 8x8 micro-tile/thread.
__global__ __launch_bounds__(256) void gemm128(const float* __restrict__ A,
                                               const float* __restrict__ W,
                                               const float* __restrict__ bias,
                                               float* __restrict__ H) {
    __shared__ float As[16][128];  // [k][m]
    __shared__ float Ws[16][128];  // [k][n]
    int tid  = threadIdx.x;
    int row0 = blockIdx.x * 128;
    int tm = tid / 16, tn = tid % 16;

    float acc[8][8];
#pragma unroll
    for (int r = 0; r < 8; ++r)
#pragma unroll
        for (int c = 0; c < 8; ++c) acc[r][c] = 0.0f;

    for (int k0 = 0; k0 < 128; k0 += 16) {
#pragma unroll
        for (int j = 0; j < 2; ++j) {
            int lin = tid * 2 + j;        // 0..511
            int r   = lin / 4;            // 0..127
            int kk  = (lin % 4) * 4;      // 0,4,8,12
            int gr  = row0 + r;
            float4 a4 = make_float4(0.f, 0.f, 0.f, 0.f);
            if (gr < N_NODES) a4 = *(const float4*)&A[(size_t)gr * CH + k0 + kk];
            As[kk + 0][r] = a4.x;
            As[kk + 1][r] = a4.y;
            As[kk + 2][r] = a4.z;
            As[kk + 3][r] = a4.w;
            int wk = lin / 32;            // 0..15
            int wc = (lin % 32) * 4;      // 0..124
            *(float4*)&Ws[wk][wc] = *(const float4*)&W[(size_t)(k0 + wk) * CH + wc];
        }
        __syncthreads();
#pragma unroll
        for (int k = 0; k < 16; ++k) {
            float4 alo = *(const float4*)&As[k][tm * 8];
            float4 ahi = *(const float4*)&As[k][tm * 8 + 4];
            float4 wlo = *(const float4*)&Ws[k][tn * 8];
            float4 whi = *(const float4*)&Ws[k][tn * 8 + 4];
            float av[8] = {alo.x, alo.y, alo.z, alo.w, ahi.x, ahi.y, ahi.z, ahi.w};
            float wv[8] = {wlo.x, wlo.y, wlo.z, wlo.w, whi.x, whi.y, whi.z, whi.w};
#pragma unroll
            for (int r = 0; r < 8; ++r)
#pragma unroll
                for (int c = 0; c < 8; ++c)
                    acc[r][c] = fmaf(av[r], wv[c], acc[r][c]);
        }
        __syncthreads();
    }

    float bv[8];
#pragma unroll
    for (int c = 0; c < 8; ++c) bv[c] = bias[tn * 8 + c];
#pragma unroll
    for (int r = 0; r < 8; ++r) {
        int gr = row0 + tm * 8 + r;
        if (gr < N_NODES) {
            float4 o0 = make_float4(acc[r][0] + bv[0], acc[r][1] + bv[1],
                                    acc[r][2] + bv[2], acc[r][3] + bv[3]);
            float4 o1 = make_float4(acc[r][4] + bv[4], acc[r][5] + bv[5],
                                    acc[r][6] + bv[6], acc[r][7] + bv[7]);
            *(float4*)&H[(size_t)gr * CH + tn * 8]     = o0;
            *(float4*)&H[(size_t)gr * CH + tn * 8 + 4] = o1;
        }
    }
}

// ---------------- edge aggregation: out[n] = self_norm*h[n] + sum_e norm*h[src] ----------------
// one wave per node; lane holds 2 channels; edges loaded cooperatively + shfl-broadcast.
__global__ __launch_bounds__(256) void agg_kernel(const float* __restrict__ h,
                                                  const int* __restrict__ csr_src,
                                                  const float* __restrict__ csr_norm,
                                                  const int* __restrict__ ptr,
                                                  const float* __restrict__ dinv,
                                                  float* __restrict__ outp,
                                                  int relu) {
    int wid  = threadIdx.x >> 6;
    int lane = threadIdx.x & 63;
    int node = blockIdx.x * 4 + wid;
    if (node >= N_NODES) return;
    int beg = ptr[node], end = ptr[node + 1];
    int c = lane * 2;
    float dn = dinv[node];
    float2 hv = *(const float2*)&h[(size_t)node * CH + c];
    float acc0 = dn * dn * hv.x;
    float acc1 = dn * dn * hv.y;
    for (int e0 = beg; e0 < end; e0 += 64) {
        int e = e0 + lane;
        int s = 0;
        float w = 0.0f;
        if (e < end) { s = csr_src[e]; w = csr_norm[e]; }
        int m = min(64, end - e0);
        for (int j = 0; j < m; ++j) {
            int   sj = __shfl(s, j);
            float wj = __shfl(w, j);
            float2 g = *(const float2*)&h[(size_t)sj * CH + c];
            acc0 = fmaf(wj, g.x, acc0);
            acc1 = fmaf(wj, g.y, acc1);
        }
    }
    if (relu) { acc0 = fmaxf(acc0, 0.0f); acc1 = fmaxf(acc1, 0.0f); }
    *(float2*)&outp[(size_t)node * CH + c] = make_float2(acc0, acc1);
}

// ---------------- global mean-pool partials ----------------
__global__ __launch_bounds__(256) void pool_kernel(const float* __restrict__ h,
                                                   const int* __restrict__ batch,
                                                   float* __restrict__ sums,
                                                   float* __restrict__ counts) {
    __shared__ float s_sum[NUM_G * CH];  // 32 KiB
    __shared__ float s_cnt[NUM_G];
    int tid = threadIdx.x;
    for (int i = tid; i < NUM_G * CH; i += 256) s_sum[i] = 0.0f;
    if (tid < NUM_G) s_cnt[tid] = 0.0f;
    __syncthreads();
    int wid = tid >> 6, lane = tid & 63;
    int c = lane * 2;
    for (int node = blockIdx.x * 4 + wid; node < N_NODES; node += gridDim.x * 4) {
        int g = batch[node];
        float2 hv = *(const float2*)&h[(size_t)node * CH + c];
        atomicAdd(&s_sum[g * CH + c],     hv.x);
        atomicAdd(&s_sum[g * CH + c + 1], hv.y);
        if (lane == 0) atomicAdd(&s_cnt[g], 1.0f);
    }
    __syncthreads();
    for (int i = tid; i < NUM_G * CH; i += 256) unsafeAtomicAdd(&sums[i], s_sum[i]);
    if (tid < NUM_G) unsafeAtomicAdd(&counts[tid], s_cnt[tid]);
}

// ---------------- final: out[g,o] = (sums[g]/cnt[g]) @ Wp + bp ----------------
__global__ __launch_bounds__(64) void out_kernel(const float* __restrict__ sums,
                                                 const float* __restrict__ counts,
                                                 const float* __restrict__ Wp,
                                                 const float* __restrict__ bp,
                                                 float* __restrict__ outp) {
    int g = blockIdx.x;
    int o = threadIdx.x;
    float inv = 1.0f / fmaxf(counts[g], 1.0f);
    float acc = bp[o];
    for (int c = 0; c < CH; ++c)
        acc = fmaf(sums[g * CH + c] * inv, Wp[c * OUT_CH + o], acc);
    outp[g * OUT_CH + o] = acc;
}

extern "C" void kernel_launch(void* const* d_in, const int* in_sizes, int n_in,
                              void* d_out, int out_size, void* d_ws, size_t ws_size,
                              hipStream_t stream) {
    (void)in_sizes; (void)n_in; (void)out_size; (void)ws_size;
    const float* x     = (const float*)d_in[0];
    const int*   ei    = (const int*)d_in[1];
    const int*   batch = (const int*)d_in[2];
    const float* W1 = (const float*)d_in[3];
    const float* b1 = (const float*)d_in[4];
    const float* W2 = (const float*)d_in[5];
    const float* b2 = (const float*)d_in[6];
    const float* W3 = (const float*)d_in[7];
    const float* b3 = (const float*)d_in[8];
    const float* Wp = (const float*)d_in[9];
    const float* bp = (const float*)d_in[10];
    float* outp = (float*)d_out;

    const int* srcp = ei;
    const int* dstp = ei + N_EDGES;

    // workspace carve-up (~117 MB)
    char* ws = (char*)d_ws;
    auto carve = [&](size_t bytes) {
        char* p = ws;
        ws += (bytes + 255) & ~(size_t)255;
        return p;
    };
    float* B0       = (float*)carve((size_t)N_NODES * CH * 4);
    float* B1       = (float*)carve((size_t)N_NODES * CH * 4);
    int*   csr_src  = (int*)carve((size_t)N_EDGES * 4);
    float* csr_norm = (float*)carve((size_t)N_EDGES * 4);
    int*   cnt      = (int*)carve((size_t)N_NODES * 4);
    int*   cursor   = (int*)carve((size_t)N_NODES * 4);
    int*   ptrA     = (int*)carve((size_t)(N_NODES + 1) * 4);
    float* dinv     = (float*)carve((size_t)N_NODES * 4);
    float* sums     = (float*)carve((size_t)NUM_G * CH * 4);
    float* counts   = (float*)carve((size_t)NUM_G * 4);

    hipMemsetAsync(cnt,    0, (size_t)N_NODES * 4, stream);
    hipMemsetAsync(cursor, 0, (size_t)N_NODES * 4, stream);
    hipMemsetAsync(sums,   0, (size_t)NUM_G * CH * 4, stream);
    hipMemsetAsync(counts, 0, (size_t)NUM_G * 4, stream);

    const int EB = (N_EDGES + 255) / 256;
    const int NB = (N_NODES + 255) / 256;
    const int GB = (N_NODES + 127) / 128;   // gemm row-blocks
    const int AB = (N_NODES + 3) / 4;       // agg: 4 nodes/block

    count_deg   <<<EB, 256, 0, stream>>>(dstp, cnt);
    compute_dinv<<<NB, 256, 0, stream>>>(cnt, dinv);
    scan_kernel <<<1, 1024, 0, stream>>>(cnt, ptrA);
    fill_csr    <<<EB, 256, 0, stream>>>(srcp, dstp, ptrA, cursor, dinv, csr_src, csr_norm);

    // layer 1
    gemm128   <<<GB, 256, 0, stream>>>(x, W1, b1, B0);
    agg_kernel<<<AB, 256, 0, stream>>>(B0, csr_src, csr_norm, ptrA, dinv, B1, 1);
    // layer 2
    gemm128   <<<GB, 256, 0, stream>>>(B1, W2, b2, B0);
    agg_kernel<<<AB, 256, 0, stream>>>(B0, csr_src, csr_norm, ptrA, dinv, B1, 1);
    // layer 3
    gemm128   <<<GB, 256, 0, stream>>>(B1, W3, b3, B0);
    agg_kernel<<<AB, 256, 0, stream>>>(B0, csr_src, csr_norm, ptrA, dinv, B1, 0);

    pool_kernel<<<256, 256, 0, stream>>>(B1, batch, sums, counts);
    out_kernel <<<NUM_G, 64, 0, stream>>>(sums, counts, Wp, bp, outp);
}

// Round 2
// 748.074 us; speedup vs baseline: 1.2901x; 1.2901x over previous
//
#include <hip/hip_runtime.h>

#define N_NODES 100000
#define N_EDGES 1600000
#define CH      128
#define OUT_CH  64
#define NUM_G   64

typedef unsigned short ushort_t;
typedef unsigned int uint_t;
typedef __attribute__((ext_vector_type(8))) short short8;
typedef __attribute__((ext_vector_type(4))) float f32x4;

__device__ __forceinline__ float b2f(ushort_t u) {
    union { uint_t i; float f; } v; v.i = ((uint_t)u) << 16; return v.f;
}
__device__ __forceinline__ ushort_t f2b(float f) {
    union { float f; uint_t i; } v; v.f = f;
    uint_t u = v.i;
    uint_t r = (u + 0x7fffu + ((u >> 16) & 1u)) >> 16;
    return (ushort_t)r;
}
__device__ __forceinline__ float blo(uint_t u) {
    union { uint_t i; float f; } v; v.i = u << 16; return v.f;
}
__device__ __forceinline__ float bhi(uint_t u) {
    union { uint_t i; float f; } v; v.i = u & 0xffff0000u; return v.f;
}

// ---------------- fp32 -> bf16 feature convert ----------------
__global__ __launch_bounds__(256) void cvt_x(const float* __restrict__ x,
                                             ushort_t* __restrict__ xb) {
    int i = blockIdx.x * 256 + threadIdx.x;          // one float4 per thread
    const int n4 = N_NODES * CH / 4;
    if (i >= n4) return;
    float4 v = *(const float4*)&x[(size_t)i * 4];
    ushort_t o0 = f2b(v.x), o1 = f2b(v.y), o2 = f2b(v.z), o3 = f2b(v.w);
    uint_t p0 = (uint_t)o0 | ((uint_t)o1 << 16);
    uint_t p1 = (uint_t)o2 | ((uint_t)o3 << 16);
    *(uint2*)&xb[(size_t)i * 4] = make_uint2(p0, p1);
}

// ---------------- W[k][n] fp32 -> Wt[n][k] bf16 ----------------
__global__ __launch_bounds__(256) void cvt_w(const float* __restrict__ W,
                                             ushort_t* __restrict__ Wt) {
    int t = blockIdx.x * 256 + threadIdx.x;
    if (t >= CH * CH) return;
    int k = t >> 7, n = t & 127;
    Wt[(size_t)n * CH + k] = f2b(W[t]);
}

// ---------------- degree count ----------------
__global__ __launch_bounds__(256) void count_deg(const int* __restrict__ dst,
                                                 int* __restrict__ cnt) {
    int e = blockIdx.x * 256 + threadIdx.x;
    if (e < N_EDGES) atomicAdd(&cnt[dst[e]], 1);
}

__global__ __launch_bounds__(256) void compute_dinv(const int* __restrict__ cnt,
                                                    float* __restrict__ dinv) {
    int n = blockIdx.x * 256 + threadIdx.x;
    if (n < N_NODES) dinv[n] = rsqrtf((float)cnt[n] + 1.0f);
}

// ---------------- single-block exclusive scan (CSR row ptr) ----------------
__global__ __launch_bounds__(1024) void scan_kernel(const int* __restrict__ cnt,
                                                    int* __restrict__ ptr) {
    __shared__ int s_w[16];
    int tid = threadIdx.x, lane = tid & 63, wid = tid >> 6;
    int run = 0;
    for (int base = 0; base < N_NODES; base += 1024) {
        int i = base + tid;
        int v = (i < N_NODES) ? cnt[i] : 0;
        int incl = v;
#pragma unroll
        for (int off = 1; off < 64; off <<= 1) {
            int t = __shfl_up(incl, off);
            if (lane >= off) incl += t;
        }
        if (lane == 63) s_w[wid] = incl;
        __syncthreads();
        if (tid < 16) {
            int w = s_w[tid];
#pragma unroll
            for (int off = 1; off < 16; off <<= 1) {
                int t = __shfl_up(w, off);
                if (tid >= off) w += t;
            }
            s_w[tid] = w;
        }
        __syncthreads();
        int woff = (wid > 0) ? s_w[wid - 1] : 0;
        if (i < N_NODES) ptr[i] = run + woff + incl - v;
        run += s_w[15];
        __syncthreads();
    }
    if (tid == 0) ptr[N_NODES] = run;
}

// ---------------- CSR fill (bucket by dst) ----------------
__global__ __launch_bounds__(256) void fill_csr(const int* __restrict__ src,
                                                const int* __restrict__ dst,
                                                const int* __restrict__ ptr,
                                                int* __restrict__ cursor,
                                                const float* __restrict__ dinv,
                                                int* __restrict__ csr_src,
                                                float* __restrict__ csr_norm) {
    int e = blockIdx.x * 256 + threadIdx.x;
    if (e >= N_EDGES) return;
    int s = src[e], d = dst[e];
    int pos = atomicAdd(&cursor[d], 1);
    int i = ptr[d] + pos;
    csr_src[i]  = s;
    csr_norm[i] = dinv[s] * dinv[d];
}

// ---------------- MFMA GEMM: H[n,128] = A[n,128] @ W[128,128] + b (bf16 in/out) ----
// block = 256 thr = 4 waves; wave computes 16 rows x 128 cols via 16x16x32 bf16 MFMA.
__global__ __launch_bounds__(256) void gemm_mfma(const ushort_t* __restrict__ A,
                                                 const ushort_t* __restrict__ Wt,
                                                 const float* __restrict__ bias,
                                                 ushort_t* __restrict__ H) {
    int wv = threadIdx.x >> 6, lane = threadIdx.x & 63;
    int q = lane >> 4, ml = lane & 15;
    int r0 = blockIdx.x * 64 + wv * 16;
    int arow = r0 + ml;
    if (arow >= N_NODES) arow = N_NODES - 1;  // clamp; stores are guarded
    const ushort_t* ap = A + (size_t)arow * CH;

    f32x4 acc[8];
#pragma unroll
    for (int ct = 0; ct < 8; ++ct) { acc[ct][0] = 0.f; acc[ct][1] = 0.f; acc[ct][2] = 0.f; acc[ct][3] = 0.f; }

#pragma unroll
    for (int ks = 0; ks < 4; ++ks) {
        short8 af = *(const short8*)(ap + ks * 32 + q * 8);
#pragma unroll
        for (int ct = 0; ct < 8; ++ct) {
            short8 bf = *(const short8*)(Wt + (size_t)(ct * 16 + ml) * CH + ks * 32 + q * 8);
            acc[ct] = __builtin_amdgcn_mfma_f32_16x16x32_bf16(af, bf, acc[ct], 0, 0, 0);
        }
    }

#pragma unroll
    for (int ct = 0; ct < 8; ++ct) {
        int col = ct * 16 + ml;
        float bv = bias[col];
#pragma unroll
        for (int i = 0; i < 4; ++i) {
            int rr = r0 + q * 4 + i;
            if (rr < N_NODES)
                H[(size_t)rr * CH + col] = f2b(acc[ct][i] + bv);
        }
    }
}

// ---------------- edge aggregation (bf16): out[n] = self + sum norm*h[src] ----------
// one wave per node; lane-group q (16 lanes) handles edge (j0+q); lane loads 8 ch (16B).
__global__ __launch_bounds__(256) void agg_bf16(const ushort_t* __restrict__ h,
                                                const int* __restrict__ csr_src,
                                                const float* __restrict__ csr_norm,
                                                const int* __restrict__ ptr,
                                                const float* __restrict__ dinv,
                                                ushort_t* __restrict__ outp,
                                                int relu) {
    int wv = threadIdx.x >> 6, lane = threadIdx.x & 63;
    int node = blockIdx.x * 4 + wv;
    if (node >= N_NODES) return;
    int q = lane >> 4;
    int c8 = (lane & 15) * 8;  // channel base (8 bf16 = 16B per lane)
    int beg = ptr[node], end = ptr[node + 1];

    float acc[8];
#pragma unroll
    for (int i = 0; i < 8; ++i) acc[i] = 0.0f;

    for (int e0 = beg; e0 < end; e0 += 64) {
        int e = e0 + lane;
        int s = 0; float w = 0.0f;
        if (e < end) { s = csr_src[e]; w = csr_norm[e]; }
        int m = min(64, end - e0);
        for (int j0 = 0; j0 < m; j0 += 4) {
            int   sj = __shfl(s, j0 + q);
            float wj = __shfl(w, j0 + q);
            uint4 u = *(const uint4*)(h + (size_t)sj * CH + c8);
            acc[0] = fmaf(wj, blo(u.x), acc[0]);
            acc[1] = fmaf(wj, bhi(u.x), acc[1]);
            acc[2] = fmaf(wj, blo(u.y), acc[2]);
            acc[3] = fmaf(wj, bhi(u.y), acc[3]);
            acc[4] = fmaf(wj, blo(u.z), acc[4]);
            acc[5] = fmaf(wj, bhi(u.z), acc[5]);
            acc[6] = fmaf(wj, blo(u.w), acc[6]);
            acc[7] = fmaf(wj, bhi(u.w), acc[7]);
        }
    }

    // merge the 4 edge-groups (lanes xor 16, 32 share the same channel slice)
#pragma unroll
    for (int i = 0; i < 8; ++i) {
        acc[i] += __shfl_xor(acc[i], 16);
        acc[i] += __shfl_xor(acc[i], 32);
    }

    // self-loop term
    float dn = dinv[node];
    float dn2 = dn * dn;
    uint4 us = *(const uint4*)(h + (size_t)node * CH + c8);
    acc[0] = fmaf(dn2, blo(us.x), acc[0]);
    acc[1] = fmaf(dn2, bhi(us.x), acc[1]);
    acc[2] = fmaf(dn2, blo(us.y), acc[2]);
    acc[3] = fmaf(dn2, bhi(us.y), acc[3]);
    acc[4] = fmaf(dn2, blo(us.z), acc[4]);
    acc[5] = fmaf(dn2, bhi(us.z), acc[5]);
    acc[6] = fmaf(dn2, blo(us.w), acc[6]);
    acc[7] = fmaf(dn2, bhi(us.w), acc[7]);

    if (relu) {
#pragma unroll
        for (int i = 0; i < 8; ++i) acc[i] = fmaxf(acc[i], 0.0f);
    }

    if (q == 0) {
        uint4 o;
        o.x = (uint_t)f2b(acc[0]) | ((uint_t)f2b(acc[1]) << 16);
        o.y = (uint_t)f2b(acc[2]) | ((uint_t)f2b(acc[3]) << 16);
        o.z = (uint_t)f2b(acc[4]) | ((uint_t)f2b(acc[5]) << 16);
        o.w = (uint_t)f2b(acc[6]) | ((uint_t)f2b(acc[7]) << 16);
        *(uint4*)(outp + (size_t)node * CH + c8) = o;
    }
}

// ---------------- global mean-pool partials (bf16 in) ----------------
__global__ __launch_bounds__(256) void pool_kernel(const ushort_t* __restrict__ h,
                                                   const int* __restrict__ batch,
                                                   float* __restrict__ sums,
                                                   float* __restrict__ counts) {
    __shared__ float s_sum[NUM_G * CH];  // 32 KiB
    __shared__ float s_cnt[NUM_G];
    int tid = threadIdx.x;
    for (int i = tid; i < NUM_G * CH; i += 256) s_sum[i] = 0.0f;
    if (tid < NUM_G) s_cnt[tid] = 0.0f;
    __syncthreads();
    int wid = tid >> 6, lane = tid & 63;
    int c = lane * 2;
    for (int node = blockIdx.x * 4 + wid; node < N_NODES; node += gridDim.x * 4) {
        int g = batch[node];
        uint_t u = *(const uint_t*)(h + (size_t)node * CH + c);
        atomicAdd(&s_sum[g * CH + c],     blo(u));
        atomicAdd(&s_sum[g * CH + c + 1], bhi(u));
        if (lane == 0) atomicAdd(&s_cnt[g], 1.0f);
    }
    __syncthreads();
    for (int i = tid; i < NUM_G * CH; i += 256) unsafeAtomicAdd(&sums[i], s_sum[i]);
    if (tid < NUM_G) unsafeAtomicAdd(&counts[tid], s_cnt[tid]);
}

// ---------------- final: out[g,o] = (sums[g]/cnt[g]) @ Wp + bp ----------------
__global__ __launch_bounds__(64) void out_kernel(const float* __restrict__ sums,
                                                 const float* __restrict__ counts,
                                                 const float* __restrict__ Wp,
                                                 const float* __restrict__ bp,
                                                 float* __restrict__ outp) {
    int g = blockIdx.x;
    int o = threadIdx.x;
    float inv = 1.0f / fmaxf(counts[g], 1.0f);
    float acc = bp[o];
    for (int c = 0; c < CH; ++c)
        acc = fmaf(sums[g * CH + c] * inv, Wp[c * OUT_CH + o], acc);
    outp[g * OUT_CH + o] = acc;
}

extern "C" void kernel_launch(void* const* d_in, const int* in_sizes, int n_in,
                              void* d_out, int out_size, void* d_ws, size_t ws_size,
                              hipStream_t stream) {
    (void)in_sizes; (void)n_in; (void)out_size; (void)ws_size;
    const float* x     = (const float*)d_in[0];
    const int*   ei    = (const int*)d_in[1];
    const int*   batch = (const int*)d_in[2];
    const float* W1 = (const float*)d_in[3];
    const float* b1 = (const float*)d_in[4];
    const float* W2 = (const float*)d_in[5];
    const float* b2 = (const float*)d_in[6];
    const float* W3 = (const float*)d_in[7];
    const float* b3 = (const float*)d_in[8];
    const float* Wp = (const float*)d_in[9];
    const float* bp = (const float*)d_in[10];
    float* outp = (float*)d_out;

    const int* srcp = ei;
    const int* dstp = ei + N_EDGES;

    char* ws = (char*)d_ws;
    auto carve = [&](size_t bytes) {
        char* p = ws;
        ws += (bytes + 255) & ~(size_t)255;
        return p;
    };
    ushort_t* X  = (ushort_t*)carve((size_t)N_NODES * CH * 2);  // 25.6 MB
    ushort_t* Hb = (ushort_t*)carve((size_t)N_NODES * CH * 2);  // 25.6 MB
    ushort_t* Ab = (ushort_t*)carve((size_t)N_NODES * CH * 2);  // 25.6 MB
    ushort_t* Wt1 = (ushort_t*)carve((size_t)CH * CH * 2);
    ushort_t* Wt2 = (ushort_t*)carve((size_t)CH * CH * 2);
    ushort_t* Wt3 = (ushort_t*)carve((size_t)CH * CH * 2);
    int*   csr_src  = (int*)carve((size_t)N_EDGES * 4);
    float* csr_norm = (float*)carve((size_t)N_EDGES * 4);
    int*   cnt      = (int*)carve((size_t)N_NODES * 4);
    int*   cursor   = (int*)carve((size_t)N_NODES * 4);
    int*   ptrA     = (int*)carve((size_t)(N_NODES + 1) * 4);
    float* dinv     = (float*)carve((size_t)N_NODES * 4);
    float* sums     = (float*)carve((size_t)NUM_G * CH * 4);
    float* counts   = (float*)carve((size_t)NUM_G * 4);

    hipMemsetAsync(cnt,    0, (size_t)N_NODES * 4, stream);
    hipMemsetAsync(cursor, 0, (size_t)N_NODES * 4, stream);
    hipMemsetAsync(sums,   0, (size_t)NUM_G * CH * 4, stream);
    hipMemsetAsync(counts, 0, (size_t)NUM_G * 4, stream);

    const int EB = (N_EDGES + 255) / 256;
    const int NB = (N_NODES + 255) / 256;
    const int XB = (N_NODES * CH / 4 + 255) / 256;
    const int WB = (CH * CH + 255) / 256;
    const int GB = (N_NODES + 63) / 64;     // mfma gemm: 64 rows/block
    const int AB = (N_NODES + 3) / 4;       // agg: 4 nodes/block

    cvt_x<<<XB, 256, 0, stream>>>(x, X);
    cvt_w<<<WB, 256, 0, stream>>>(W1, Wt1);
    cvt_w<<<WB, 256, 0, stream>>>(W2, Wt2);
    cvt_w<<<WB, 256, 0, stream>>>(W3, Wt3);

    count_deg   <<<EB, 256, 0, stream>>>(dstp, cnt);
    compute_dinv<<<NB, 256, 0, stream>>>(cnt, dinv);
    scan_kernel <<<1, 1024, 0, stream>>>(cnt, ptrA);
    fill_csr    <<<EB, 256, 0, stream>>>(srcp, dstp, ptrA, cursor, dinv, csr_src, csr_norm);

    // layer 1
    gemm_mfma<<<GB, 256, 0, stream>>>(X, Wt1, b1, Hb);
    agg_bf16 <<<AB, 256, 0, stream>>>(Hb, csr_src, csr_norm, ptrA, dinv, Ab, 1);
    // layer 2
    gemm_mfma<<<GB, 256, 0, stream>>>(Ab, Wt2, b2, Hb);
    agg_bf16 <<<AB, 256, 0, stream>>>(Hb, csr_src, csr_norm, ptrA, dinv, X, 1);
    // layer 3
    gemm_mfma<<<GB, 256, 0, stream>>>(X, Wt3, b3, Hb);
    agg_bf16 <<<AB, 256, 0, stream>>>(Hb, csr_src, csr_norm, ptrA, dinv, Ab, 0);

    pool_kernel<<<256, 256, 0, stream>>>(Ab, batch, sums, counts);
    out_kernel <<<NUM_G, 64, 0, stream>>>(sums, counts, Wp, bp, outp);
}

// Round 3
// 615.944 us; speedup vs baseline: 1.5669x; 1.2145x over previous
//
#include <hip/hip_runtime.h>

#define N_NODES 100000
#define N_EDGES 1600000
#define CH      128
#define OUT_CH  64
#define NUM_G   64

typedef unsigned short ushort_t;
typedef unsigned int uint_t;
typedef __attribute__((ext_vector_type(8))) short short8;
typedef __attribute__((ext_vector_type(4))) float f32x4;

#define XB 12500            // cvt_x blocks (100000*128/4/256)
#define WB 64               // cvt_w blocks per weight (128*128/256)
#define EB 6250             // edge blocks (1600000/256)
#define GB ((N_NODES + 63) / 64)   // gemm row-blocks (64 rows/block)
#define AB ((N_NODES + 3) / 4)     // agg blocks (4 nodes/block)
#define SB 98               // scan blocks (ceil(100000/1024))

__device__ __forceinline__ ushort_t f2b(float f) {
    union { float f; uint_t i; } v; v.f = f;
    uint_t u = v.i;
    uint_t r = (u + 0x7fffu + ((u >> 16) & 1u)) >> 16;
    return (ushort_t)r;
}
__device__ __forceinline__ float blo(uint_t u) {
    union { uint_t i; float f; } v; v.i = u << 16; return v.f;
}
__device__ __forceinline__ float bhi(uint_t u) {
    union { uint_t i; float f; } v; v.i = u & 0xffff0000u; return v.f;
}

// ---------------- fused prep: cvt_x | cvt_w x3 | count_deg(+pos) ----------------
__global__ __launch_bounds__(256) void prep_kernel(const float* __restrict__ x,
                                                   ushort_t* __restrict__ xb,
                                                   const float* __restrict__ W1,
                                                   const float* __restrict__ W2,
                                                   const float* __restrict__ W3,
                                                   ushort_t* __restrict__ Wt1,
                                                   ushort_t* __restrict__ Wt2,
                                                   ushort_t* __restrict__ Wt3,
                                                   const int* __restrict__ dst,
                                                   int* __restrict__ cnt,
                                                   int* __restrict__ pos) {
    int b = blockIdx.x, tid = threadIdx.x;
    if (b < XB) {
        int i = b * 256 + tid;                        // one float4 per thread
        float4 v = *(const float4*)&x[(size_t)i * 4];
        uint_t p0 = (uint_t)f2b(v.x) | ((uint_t)f2b(v.y) << 16);
        uint_t p1 = (uint_t)f2b(v.z) | ((uint_t)f2b(v.w) << 16);
        *(uint2*)&xb[(size_t)i * 4] = make_uint2(p0, p1);
    } else if (b < XB + 3 * WB) {
        int wi = (b - XB) / WB;
        const float* W  = (wi == 0) ? W1 : (wi == 1) ? W2 : W3;
        ushort_t*   Wt = (wi == 0) ? Wt1 : (wi == 1) ? Wt2 : Wt3;
        int t = ((b - XB) % WB) * 256 + tid;
        int k = t >> 7, n = t & 127;
        Wt[(size_t)n * CH + k] = f2b(W[t]);
    } else {
        int e = (b - XB - 3 * WB) * 256 + tid;
        if (e < N_EDGES) pos[e] = atomicAdd(&cnt[dst[e]], 1);
    }
}

// ---------------- 3-phase scan (+dinv fused into phase 1) ----------------
__device__ __forceinline__ int wave_incl_scan(int v, int lane) {
#pragma unroll
    for (int off = 1; off < 64; off <<= 1) {
        int t = __shfl_up(v, off);
        if (lane >= off) v += t;
    }
    return v;
}

__global__ __launch_bounds__(1024) void scan_p1(const int* __restrict__ cnt,
                                                int* __restrict__ ptr,
                                                int* __restrict__ bsum,
                                                float* __restrict__ dinv) {
    __shared__ int s_w[16];
    int tid = threadIdx.x, lane = tid & 63, wid = tid >> 6;
    int i = blockIdx.x * 1024 + tid;
    int v = (i < N_NODES) ? cnt[i] : 0;
    if (i < N_NODES) dinv[i] = rsqrtf((float)v + 1.0f);
    int incl = wave_incl_scan(v, lane);
    if (lane == 63) s_w[wid] = incl;
    __syncthreads();
    if (tid < 16) {
        int w = s_w[tid];
#pragma unroll
        for (int off = 1; off < 16; off <<= 1) {
            int t = __shfl_up(w, off);
            if (tid >= off) w += t;
        }
        s_w[tid] = w;
    }
    __syncthreads();
    int woff = (wid > 0) ? s_w[wid - 1] : 0;
    if (i < N_NODES) ptr[i] = woff + incl - v;     // block-local exclusive
    if (tid == 0) bsum[blockIdx.x] = s_w[15];
}

__global__ __launch_bounds__(128) void scan_p2(const int* __restrict__ bsum,
                                               int* __restrict__ boff,
                                               int* __restrict__ ptr) {
    __shared__ int s_w[2];
    int tid = threadIdx.x, lane = tid & 63, wid = tid >> 6;
    int v = (tid < SB) ? bsum[tid] : 0;
    int incl = wave_incl_scan(v, lane);
    if (lane == 63) s_w[wid] = incl;
    __syncthreads();
    int woff = (wid == 1) ? s_w[0] : 0;
    int excl = woff + incl - v;
    if (tid < SB) boff[tid] = excl;
    if (tid == SB - 1) ptr[N_NODES] = excl + v;
}

__global__ __launch_bounds__(1024) void scan_p3(int* __restrict__ ptr,
                                                const int* __restrict__ boff) {
    int i = blockIdx.x * 1024 + threadIdx.x;
    if (i < N_NODES) ptr[i] += boff[blockIdx.x];
}

// ---------------- MFMA GEMM body (device) ----------------
__device__ __forceinline__ void gemm_body(int bid, int tid,
                                          const ushort_t* __restrict__ A,
                                          const ushort_t* __restrict__ Wt,
                                          const float* __restrict__ bias,
                                          ushort_t* __restrict__ H) {
    int wv = tid >> 6, lane = tid & 63;
    int q = lane >> 4, ml = lane & 15;
    int r0 = bid * 64 + wv * 16;
    int arow = r0 + ml;
    if (arow >= N_NODES) arow = N_NODES - 1;  // clamp; stores guarded
    const ushort_t* ap = A + (size_t)arow * CH;

    f32x4 acc[8];
#pragma unroll
    for (int ct = 0; ct < 8; ++ct) { acc[ct][0] = 0.f; acc[ct][1] = 0.f; acc[ct][2] = 0.f; acc[ct][3] = 0.f; }

#pragma unroll
    for (int ks = 0; ks < 4; ++ks) {
        short8 af = *(const short8*)(ap + ks * 32 + q * 8);
#pragma unroll
        for (int ct = 0; ct < 8; ++ct) {
            short8 bf = *(const short8*)(Wt + (size_t)(ct * 16 + ml) * CH + ks * 32 + q * 8);
            acc[ct] = __builtin_amdgcn_mfma_f32_16x16x32_bf16(af, bf, acc[ct], 0, 0, 0);
        }
    }

#pragma unroll
    for (int ct = 0; ct < 8; ++ct) {
        int col = ct * 16 + ml;
        float bv = bias[col];
#pragma unroll
        for (int i = 0; i < 4; ++i) {
            int rr = r0 + q * 4 + i;
            if (rr < N_NODES)
                H[(size_t)rr * CH + col] = f2b(acc[ct][i] + bv);
        }
    }
}

// ---------------- fused: CSR fill | gemm layer-1 ----------------
__global__ __launch_bounds__(256) void fill_gemm1(const int* __restrict__ src,
                                                  const int* __restrict__ dst,
                                                  const int* __restrict__ ptr,
                                                  const int* __restrict__ pos,
                                                  int* __restrict__ csr_src,
                                                  const ushort_t* __restrict__ A,
                                                  const ushort_t* __restrict__ Wt,
                                                  const float* __restrict__ bias,
                                                  ushort_t* __restrict__ H) {
    if (blockIdx.x < EB) {
        int e = blockIdx.x * 256 + threadIdx.x;
        if (e < N_EDGES) {
            int d = dst[e];
            csr_src[ptr[d] + pos[e]] = src[e];
        }
    } else {
        gemm_body(blockIdx.x - EB, threadIdx.x, A, Wt, bias, H);
    }
}

__global__ __launch_bounds__(256) void gemm_mfma(const ushort_t* __restrict__ A,
                                                 const ushort_t* __restrict__ Wt,
                                                 const float* __restrict__ bias,
                                                 ushort_t* __restrict__ H) {
    gemm_body(blockIdx.x, threadIdx.x, A, Wt, bias, H);
}

// ---------------- edge aggregation (bf16, norm on the fly) ----------------
// out[n] = dn*(sum_e dinv[s]*h[s] + dn*h[n]); one wave/node, 4 edges in flight.
__global__ __launch_bounds__(256) void agg_bf16(const ushort_t* __restrict__ h,
                                                const int* __restrict__ csr_src,
                                                const int* __restrict__ ptr,
                                                const float* __restrict__ dinv,
                                                ushort_t* __restrict__ outp,
                                                int relu) {
    int wv = threadIdx.x >> 6, lane = threadIdx.x & 63;
    int node = blockIdx.x * 4 + wv;
    if (node >= N_NODES) return;
    int q = lane >> 4;
    int c8 = (lane & 15) * 8;  // 8 bf16 = 16B per lane
    int beg = ptr[node], end = ptr[node + 1];

    float acc[8];
#pragma unroll
    for (int i = 0; i < 8; ++i) acc[i] = 0.0f;

    for (int e0 = beg; e0 < end; e0 += 64) {
        int e = e0 + lane;
        int s = 0; float w = 0.0f;
        if (e < end) { s = csr_src[e]; w = dinv[s]; }
        int m = min(64, end - e0);
        for (int j0 = 0; j0 < m; j0 += 4) {
            int   sj = __shfl(s, j0 + q);
            float wj = __shfl(w, j0 + q);
            uint4 u = *(const uint4*)(h + (size_t)sj * CH + c8);
            acc[0] = fmaf(wj, blo(u.x), acc[0]);
            acc[1] = fmaf(wj, bhi(u.x), acc[1]);
            acc[2] = fmaf(wj, blo(u.y), acc[2]);
            acc[3] = fmaf(wj, bhi(u.y), acc[3]);
            acc[4] = fmaf(wj, blo(u.z), acc[4]);
            acc[5] = fmaf(wj, bhi(u.z), acc[5]);
            acc[6] = fmaf(wj, blo(u.w), acc[6]);
            acc[7] = fmaf(wj, bhi(u.w), acc[7]);
        }
    }

#pragma unroll
    for (int i = 0; i < 8; ++i) {
        acc[i] += __shfl_xor(acc[i], 16);
        acc[i] += __shfl_xor(acc[i], 32);
    }

    float dn = dinv[node];
    uint4 us = *(const uint4*)(h + (size_t)node * CH + c8);
    // out = dn*(acc + dn*h_self)
    acc[0] = dn * fmaf(dn, blo(us.x), acc[0]);
    acc[1] = dn * fmaf(dn, bhi(us.x), acc[1]);
    acc[2] = dn * fmaf(dn, blo(us.y), acc[2]);
    acc[3] = dn * fmaf(dn, bhi(us.y), acc[3]);
    acc[4] = dn * fmaf(dn, blo(us.z), acc[4]);
    acc[5] = dn * fmaf(dn, bhi(us.z), acc[5]);
    acc[6] = dn * fmaf(dn, blo(us.w), acc[6]);
    acc[7] = dn * fmaf(dn, bhi(us.w), acc[7]);

    if (relu) {
#pragma unroll
        for (int i = 0; i < 8; ++i) acc[i] = fmaxf(acc[i], 0.0f);
    }

    if (q == 0) {
        uint4 o;
        o.x = (uint_t)f2b(acc[0]) | ((uint_t)f2b(acc[1]) << 16);
        o.y = (uint_t)f2b(acc[2]) | ((uint_t)f2b(acc[3]) << 16);
        o.z = (uint_t)f2b(acc[4]) | ((uint_t)f2b(acc[5]) << 16);
        o.w = (uint_t)f2b(acc[6]) | ((uint_t)f2b(acc[7]) << 16);
        *(uint4*)(outp + (size_t)node * CH + c8) = o;
    }
}

// ---------------- global mean-pool partials (bf16 in) ----------------
__global__ __launch_bounds__(256) void pool_kernel(const ushort_t* __restrict__ h,
                                                   const int* __restrict__ batch,
                                                   float* __restrict__ sums,
                                                   float* __restrict__ counts) {
    __shared__ float s_sum[NUM_G * CH];  // 32 KiB
    __shared__ float s_cnt[NUM_G];
    int tid = threadIdx.x;
    for (int i = tid; i < NUM_G * CH; i += 256) s_sum[i] = 0.0f;
    if (tid < NUM_G) s_cnt[tid] = 0.0f;
    __syncthreads();
    int wid = tid >> 6, lane = tid & 63;
    int c = lane * 2;
    for (int node = blockIdx.x * 4 + wid; node < N_NODES; node += gridDim.x * 4) {
        int g = batch[node];
        uint_t u = *(const uint_t*)(h + (size_t)node * CH + c);
        atomicAdd(&s_sum[g * CH + c],     blo(u));
        atomicAdd(&s_sum[g * CH + c + 1], bhi(u));
        if (lane == 0) atomicAdd(&s_cnt[g], 1.0f);
    }
    __syncthreads();
    for (int i = tid; i < NUM_G * CH; i += 256) unsafeAtomicAdd(&sums[i], s_sum[i]);
    if (tid < NUM_G) unsafeAtomicAdd(&counts[tid], s_cnt[tid]);
}

// ---------------- final: out[g,o] = (sums[g]/cnt[g]) @ Wp + bp ----------------
__global__ __launch_bounds__(64) void out_kernel(const float* __restrict__ sums,
                                                 const float* __restrict__ counts,
                                                 const float* __restrict__ Wp,
                                                 const float* __restrict__ bp,
                                                 float* __restrict__ outp) {
    int g = blockIdx.x;
    int o = threadIdx.x;
    float inv = 1.0f / fmaxf(counts[g], 1.0f);
    float acc = bp[o];
    for (int c = 0; c < CH; ++c)
        acc = fmaf(sums[g * CH + c] * inv, Wp[c * OUT_CH + o], acc);
    outp[g * OUT_CH + o] = acc;
}

extern "C" void kernel_launch(void* const* d_in, const int* in_sizes, int n_in,
                              void* d_out, int out_size, void* d_ws, size_t ws_size,
                              hipStream_t stream) {
    (void)in_sizes; (void)n_in; (void)out_size; (void)ws_size;
    const float* x     = (const float*)d_in[0];
    const int*   ei    = (const int*)d_in[1];
    const int*   batch = (const int*)d_in[2];
    const float* W1 = (const float*)d_in[3];
    const float* b1 = (const float*)d_in[4];
    const float* W2 = (const float*)d_in[5];
    const float* b2 = (const float*)d_in[6];
    const float* W3 = (const float*)d_in[7];
    const float* b3 = (const float*)d_in[8];
    const float* Wp = (const float*)d_in[9];
    const float* bp = (const float*)d_in[10];
    float* outp = (float*)d_out;

    const int* srcp = ei;
    const int* dstp = ei + N_EDGES;

    char* ws = (char*)d_ws;
    auto carve = [&](size_t bytes) {
        char* p = ws;
        ws += (bytes + 255) & ~(size_t)255;
        return p;
    };
    ushort_t* X  = (ushort_t*)carve((size_t)N_NODES * CH * 2);  // 25.6 MB
    ushort_t* Hb = (ushort_t*)carve((size_t)N_NODES * CH * 2);  // 25.6 MB
    ushort_t* Ab = (ushort_t*)carve((size_t)N_NODES * CH * 2);  // 25.6 MB
    ushort_t* Wt1 = (ushort_t*)carve((size_t)CH * CH * 2);
    ushort_t* Wt2 = (ushort_t*)carve((size_t)CH * CH * 2);
    ushort_t* Wt3 = (ushort_t*)carve((size_t)CH * CH * 2);
    int*   csr_src  = (int*)carve((size_t)N_EDGES * 4);
    int*   pos      = (int*)carve((size_t)N_EDGES * 4);
    int*   cnt      = (int*)carve((size_t)N_NODES * 4);
    int*   ptrA     = (int*)carve((size_t)(N_NODES + 1) * 4);
    float* dinv     = (float*)carve((size_t)N_NODES * 4);
    int*   bsum     = (int*)carve((size_t)SB * 4);
    int*   boff     = (int*)carve((size_t)SB * 4);
    float* sums     = (float*)carve((size_t)NUM_G * CH * 4);
    float* counts   = (float*)carve((size_t)NUM_G * 4);

    hipMemsetAsync(cnt,    0, (size_t)N_NODES * 4, stream);
    hipMemsetAsync(sums,   0, (size_t)NUM_G * CH * 4, stream);
    hipMemsetAsync(counts, 0, (size_t)NUM_G * 4, stream);

    prep_kernel<<<XB + 3 * WB + EB, 256, 0, stream>>>(x, X, W1, W2, W3, Wt1, Wt2, Wt3,
                                                      dstp, cnt, pos);
    scan_p1<<<SB, 1024, 0, stream>>>(cnt, ptrA, bsum, dinv);
    scan_p2<<<1, 128, 0, stream>>>(bsum, boff, ptrA);
    scan_p3<<<SB, 1024, 0, stream>>>(ptrA, boff);

    // CSR fill overlapped with layer-1 GEMM
    fill_gemm1<<<EB + GB, 256, 0, stream>>>(srcp, dstp, ptrA, pos, csr_src,
                                            X, Wt1, b1, Hb);
    agg_bf16 <<<AB, 256, 0, stream>>>(Hb, csr_src, ptrA, dinv, Ab, 1);
    // layer 2
    gemm_mfma<<<GB, 256, 0, stream>>>(Ab, Wt2, b2, Hb);
    agg_bf16 <<<AB, 256, 0, stream>>>(Hb, csr_src, ptrA, dinv, X, 1);
    // layer 3
    gemm_mfma<<<GB, 256, 0, stream>>>(X, Wt3, b3, Hb);
    agg_bf16 <<<AB, 256, 0, stream>>>(Hb, csr_src, ptrA, dinv, Ab, 0);

    pool_kernel<<<256, 256, 0, stream>>>(Ab, batch, sums, counts);
    out_kernel <<<NUM_G, 64, 0, stream>>>(sums, counts, Wp, bp, outp);
}